// Round 10
// baseline (230.563 us; speedup 1.0000x reference)
//
#include <hip/hip_runtime.h>
#include <hip/hip_bf16.h>
#include <math.h>

#define NROWS 32768
#define DD    1024
#define EE    640
#define VV    320
#define KT    32      // DD/32
#define CTN   40      // EE/16

typedef __attribute__((ext_vector_type(8))) short short8;
typedef __attribute__((ext_vector_type(4))) float float4v;

static __device__ __forceinline__ unsigned short f2bf(float f) {
    unsigned int u = __float_as_uint(f);
    return (unsigned short)((u + 0x7fffu + ((u >> 16) & 1u)) >> 16); // RNE
}
static __device__ __forceinline__ float bf2f(unsigned short h) {
    return __uint_as_float(((unsigned int)h) << 16);
}
// hardware cvt: 8 fp32 -> 8 bf16 (v_cvt_pk_bf16_f32, RNE) — same rounding as f2bf
static __device__ __forceinline__ short8 cvt8(float4 a, float4 b) {
    float2 f0 = {a.x, a.y}, f1 = {a.z, a.w}, f2 = {b.x, b.y}, f3 = {b.z, b.w};
    union { __hip_bfloat162 h[4]; short8 s; } u;
    u.h[0] = __float22bfloat162_rn(f0);
    u.h[1] = __float22bfloat162_rn(f1);
    u.h[2] = __float22bfloat162_rn(f2);
    u.h[3] = __float22bfloat162_rn(f3);
    return u.s;
}
static __device__ __forceinline__ void gload_lds16(const void* g, void* l) {
    __builtin_amdgcn_global_load_lds(
        (const __attribute__((address_space(1))) unsigned int*)g,
        (__attribute__((address_space(3))) unsigned int*)l, 16, 0, 0);
}

// Pack W [K=1024][N=640] fp32 -> bf16, MFMA fragment layout:
// frag(kt, ct): lane l, elem e  <=  W[kt*32 + (l>>4)*8 + e][ct*16 + (l&15)]
__global__ void pack_w(const float* __restrict__ W, unsigned short* __restrict__ bp)
{
    const int t = threadIdx.x;
    const int tile = blockIdx.x * 4 + (t >> 6);   // 0..1279 = kt*40+ct
    const int lane = t & 63;
    const int kt = tile / CTN, ct = tile % CTN;
    const int k0 = kt * 32 + (lane >> 4) * 8;
    const int col = ct * 16 + (lane & 15);
    unsigned short v1[8];
    #pragma unroll
    for (int e = 0; e < 8; ++e)
        v1[e] = f2bf(W[(size_t)(k0 + e) * EE + col]);
    *(short8*)(bp + ((size_t)tile * 64 + lane) * 8) = *(const short8*)v1;
}

// GEMM: 512 blocks x 512 threads = 2 blocks/CU. Block: 64 rows x 640 cols.
// Wave = cg (0..7): all 64 rows (rf 0..3) x cols cg*80..+79 (5 frags). acc[4][5].
// A: JIT per-lane global loads (L1-shared across 8 waves, no LDS, no A-barrier).
// B: 2x40KB LDS dbuf (=80KB exactly), stage issued BEFORE compute, one
// vmcnt(0)+s_barrier per kt. Two independent blocks/CU overlap barrier drains.
__global__ __launch_bounds__(512, 4) void gemm_z2(
    const float* __restrict__ x, const unsigned short* __restrict__ bp,
    const float* __restrict__ bias, unsigned short* __restrict__ z)
{
    __shared__ unsigned short Bs[2][32 * EE];     // 80 KB exactly

    const int t    = threadIdx.x;
    const int lane = t & 63;
    const int cg   = t >> 6;
    const int n0   = blockIdx.x * 64;

    float4v acc[4][5];
    #pragma unroll
    for (int rf = 0; rf < 4; ++rf)
        #pragma unroll
        for (int ct = 0; ct < 5; ++ct)
            acc[rf][ct] = (float4v)0.f;

    // A addressing: lane l, elem e <= x[n0 + rf*16 + (l&15)][kt*32 + (l>>4)*8 + e]
    const float* xl = x + (size_t)(n0 + (lane & 15)) * DD + (lane >> 4) * 8;

    auto stageB = [&](int bb, int kt) {
        const unsigned short* src = bp + (size_t)kt * (32 * EE);
        #pragma unroll
        for (int s = 0; s < 5; ++s) {
            const int q = s * 512 + t;
            gload_lds16(src + (size_t)q * 8, &Bs[bb][q * 8]);
        }
    };

    stageB(0, 0);
    for (int kt = 0; kt < KT; ++kt) {
        // my stage ops landed; barrier => everyone's landed AND prior reads done
        asm volatile("s_waitcnt vmcnt(0)" ::: "memory");
        __builtin_amdgcn_s_barrier();
        __builtin_amdgcn_sched_barrier(0);
        if (kt + 1 < KT) stageB((kt + 1) & 1, kt + 1);   // flies across this iter
        __builtin_amdgcn_sched_barrier(0);

        short8 af[4];
        #pragma unroll
        for (int rf = 0; rf < 4; ++rf) {
            float4 a0 = *(const float4*)(xl + (size_t)rf * 16 * DD + kt * 32);
            float4 a1 = *(const float4*)(xl + (size_t)rf * 16 * DD + kt * 32 + 4);
            af[rf] = cvt8(a0, a1);
        }
        #pragma unroll
        for (int ct = 0; ct < 5; ++ct) {
            short8 bf = *(const short8*)&Bs[kt & 1][((cg*5 + ct)*64 + lane)*8];
            #pragma unroll
            for (int rf = 0; rf < 4; ++rf)
                acc[rf][ct] = __builtin_amdgcn_mfma_f32_16x16x32_bf16(af[rf], bf, acc[rf][ct], 0, 0, 0);
        }
    }

    // bias + bf16 z store. 16-lane groups write 32B runs; ct-loop covers 160B
    // contiguous per row => L2 write-combines to full lines.
    float bv[5];
    const int cb0 = cg * 80 + (lane & 15);
    #pragma unroll
    for (int ct = 0; ct < 5; ++ct) bv[ct] = bias[cb0 + ct*16];
    #pragma unroll
    for (int rf = 0; rf < 4; ++rf) {
        #pragma unroll
        for (int r = 0; r < 4; ++r) {
            const size_t n = (size_t)(n0 + rf*16 + ((lane >> 4) << 2) + r);
            #pragma unroll
            for (int ct = 0; ct < 5; ++ct)
                z[n*EE + cb0 + ct*16] = f2bf(acc[rf][ct][r] + bv[ct]);
        }
    }
}

// EPI: 2048 blocks x 512 threads; block = 16 rows. All global access coalesced
// via LDS staging; probs via transposed no-atomic column pass.
__global__ __launch_bounds__(512, 2) void epi2(
    const unsigned short* __restrict__ z, const float* __restrict__ gum,
    const float* __restrict__ cb, float* __restrict__ out,
    float* __restrict__ probs_rep)
{
    __shared__ unsigned short zs[16 * EE];   // 20 KB   zs[r*640 + c]
    __shared__ float          gs[16 * EE];   // 40 KB   gs[r*640 + g*320 + v]
    __shared__ float inv[16][2];
    __shared__ int   sidx[16][2];

    const int t = threadIdx.x;
    const size_t r0 = (size_t)blockIdx.x * 16;

    // ---- coalesced staging ----
    {
        const uint4* src = (const uint4*)(z + r0 * EE);      // 1280 x 16B
        uint4* dst = (uint4*)zs;
        dst[t]       = src[t];
        dst[t + 512] = src[t + 512];
        if (t < 256) dst[t + 1024] = src[t + 1024];
        const uint4* gsrc = (const uint4*)(gum + r0 * 2 * VV); // 2560 x 16B
        uint4* gdst = (uint4*)gs;
        #pragma unroll
        for (int s = 0; s < 5; ++s) gdst[t + s*512] = gsrc[t + s*512];
    }
    __syncthreads();

    // ---- phase 1: per (row,g) gumbel-argmax + clean exp-sum ----
    {
        const int row = t >> 5, j = t & 31, g = j >> 4, vb = (j & 15) * 20;
        const unsigned short* zrow = &zs[row * EE + g * VV + vb];
        const float* grow = &gs[row * EE + g * VV + vb];
        float m1 = -1e30f; int bi = 0; float es = 0.f;
        #pragma unroll
        for (int k = 0; k < 20; ++k) {
            const float zj = bf2f(zrow[k]);
            const float zg = zj + grow[k];
            if (zg > m1) { m1 = zg; bi = vb + k; }   // ascending: > keeps first
            es += __expf(zj);
        }
        #pragma unroll
        for (int off = 1; off < 16; off <<= 1) {     // within 16-lane group
            float om = __shfl_xor(m1, off);
            int   ob = __shfl_xor(bi, off);
            if (om > m1 || (om == m1 && ob < bi)) { m1 = om; bi = ob; }
            es += __shfl_xor(es, off);
        }
        if ((j & 15) == 0) { sidx[row][g] = bi; inv[row][g] = 1.f / es; }
    }
    __syncthreads();

    // ---- phase 2: probs, transposed (thread owns cols; zero atomic contention) ----
    {
        const int rep = blockIdx.x & 7;
        int c = t;
        {
            const int gg = (c >= VV);
            float s = 0.f;
            #pragma unroll
            for (int rr = 0; rr < 16; ++rr)
                s += __expf(bf2f(zs[rr * EE + c])) * inv[rr][gg];
            atomicAdd(&probs_rep[rep * EE + c], s);
        }
        if (t < 128) {
            c = 512 + t;
            float s = 0.f;
            #pragma unroll
            for (int rr = 0; rr < 16; ++rr)
                s += __expf(bf2f(zs[rr * EE + c])) * inv[rr][1];
            atomicAdd(&probs_rep[rep * EE + c], s);
        }
    }

    // ---- phase 3: codebook gather + coalesced out-write ----
    for (int i = t; i < 16 * 256; i += 512) {
        const int rr = i >> 8, f4 = i & 255;
        const int gg = f4 >> 7;
        const int idx = sidx[rr][gg];
        const float4 v = *(const float4*)&cb[((size_t)gg*VV + idx)*512 + (size_t)(f4 & 127)*4];
        *(float4*)&out[(r0 + rr)*DD + (size_t)f4*4] = v;
    }
}

// perplexity from 8-replica probs accumulator
__global__ void perp8_kernel(const float* __restrict__ probs_rep,
                             float* __restrict__ outp)
{
    __shared__ float s0[4], s1[4];
    int t = threadIdx.x;   // 256
    float p0 = 0.f, p1 = 0.f;
    for (int c = t; c < EE; c += 256) {
        float a = 0.f;
        #pragma unroll
        for (int rp = 0; rp < 8; ++rp) a += probs_rep[rp*EE + c];
        a *= (1.0f / NROWS);
        float v = a * logf(a + 1e-7f);
        if (c < VV) p0 += v; else p1 += v;
    }
    #pragma unroll
    for (int off = 1; off < 64; off <<= 1) {
        p0 += __shfl_xor(p0, off);
        p1 += __shfl_xor(p1, off);
    }
    if ((t & 63) == 0) { s0[t >> 6] = p0; s1[t >> 6] = p1; }
    __syncthreads();
    if (t == 0) {
        float a0 = s0[0] + s0[1] + s0[2] + s0[3];
        float a1 = s1[0] + s1[1] + s1[2] + s1[3];
        outp[0] = 0.5f * (expf(-a0) + expf(-a1));
    }
}

extern "C" void kernel_launch(void* const* d_in, const int* in_sizes, int n_in,
                              void* d_out, int out_size, void* d_ws, size_t ws_size,
                              hipStream_t stream)
{
    const float* x   = (const float*)d_in[0];
    const float* W   = (const float*)d_in[1];
    const float* b   = (const float*)d_in[2];
    const float* cb  = (const float*)d_in[3];
    const float* gum = (const float*)d_in[4];
    float* out = (float*)d_out;

    // ws layout: [bp 1.31MB][probs_rep 20KB][z 41.9MB]
    char* wsp = (char*)d_ws;
    unsigned short* bp = (unsigned short*)wsp;
    const size_t bp_b = (size_t)DD*EE*2;
    float* probs_rep = (float*)(wsp + bp_b);
    const size_t pr_b = 8*EE*sizeof(float);
    unsigned short* z = (unsigned short*)(wsp + bp_b + pr_b);

    hipMemsetAsync(probs_rep, 0, pr_b, stream);
    pack_w<<<320, 256, 0, stream>>>(W, bp);
    gemm_z2<<<NROWS / 64, 512, 0, stream>>>(x, bp, b, z);
    epi2<<<NROWS / 16, 512, 0, stream>>>(z, gum, cb, out, probs_rep);
    perp8_kernel<<<1, 256, 0, stream>>>(probs_rep, out + (out_size - 1));
}

// Round 11
// 189.288 us; speedup vs baseline: 1.2181x; 1.2181x over previous
//
#include <hip/hip_runtime.h>
#include <hip/hip_bf16.h>
#include <math.h>

#define NROWS 32768
#define DD    1024
#define EE    640
#define VV    320
#define KT    32      // DD/32
#define CTN   40      // EE/16

typedef __attribute__((ext_vector_type(8))) short short8;
typedef __attribute__((ext_vector_type(4))) short short4v;
typedef __attribute__((ext_vector_type(4))) float float4v;

static __device__ __forceinline__ unsigned short f2bf(float f) {
    unsigned int u = __float_as_uint(f);
    return (unsigned short)((u + 0x7fffu + ((u >> 16) & 1u)) >> 16); // RNE
}
static __device__ __forceinline__ float bf2f(unsigned short h) {
    return __uint_as_float(((unsigned int)h) << 16);
}
static __device__ __forceinline__ void gload_lds16(const void* g, void* l) {
    __builtin_amdgcn_global_load_lds(
        (const __attribute__((address_space(1))) unsigned int*)g,
        (__attribute__((address_space(3))) unsigned int*)l, 16, 0, 0);
}

// Pack W [K=1024][N=640] fp32 -> bf16, MFMA fragment layout:
// frag(kt, ct): lane l, elem e  <=  W[kt*32 + (l>>4)*8 + e][ct*16 + (l&15)]
__global__ void pack_w(const float* __restrict__ W, unsigned short* __restrict__ bp)
{
    const int t = threadIdx.x;
    const int tile = blockIdx.x * 4 + (t >> 6);   // 0..1279 = kt*40+ct
    const int lane = t & 63;
    const int kt = tile / CTN, ct = tile % CTN;
    const int k0 = kt * 32 + (lane >> 4) * 8;
    const int col = ct * 16 + (lane & 15);
    unsigned short v1[8];
    #pragma unroll
    for (int e = 0; e < 8; ++e)
        v1[e] = f2bf(W[(size_t)(k0 + e) * EE + col]);
    *(short8*)(bp + ((size_t)tile * 64 + lane) * 8) = *(const short8*)v1;
}

// GEMM: 512 blocks x 512 threads = 2 blocks/CU (LDS 76KB). Block: 128 rows x
// 320 cols (half of E). 8 waves: rg=w>>2 (64-row half), cg=w&3 (80 cols).
// acc[4][5]. B: 3x20KB LDS ring via global_load_lds, counted vmcnt(5);
// A: 2x8KB dbuf, coalesced fp32 loads 2 tiles ahead. R9 pipeline, halved tile.
__global__ __launch_bounds__(512, 4) void gemm_z3(
    const float* __restrict__ x, const unsigned short* __restrict__ bp,
    const float* __restrict__ bias, unsigned short* __restrict__ z)
{
    __shared__ unsigned short Bs[3][32 * VV];     // 3 x 20 KB ring
    __shared__ unsigned short As[2][128 * 32];    // 2 x 8 KB

    const int t    = threadIdx.x;
    const int lane = t & 63;
    const int w    = t >> 6;            // 0..7
    const int rg   = w >> 2;            // 64-row half
    const int cg   = w & 3;             // 80-col group within the 320-col half

    // bijective XCD swizzle (512 = 8*64): XCD k owns contiguous row-tile range
    const int swz  = (blockIdx.x & 7) * 64 + (blockIdx.x >> 3);
    const int n0   = (swz >> 1) * 128;
    const int half = swz & 1;

    float4v acc[4][5];
    #pragma unroll
    for (int rf = 0; rf < 4; ++rf)
        #pragma unroll
        for (int ct = 0; ct < 5; ++ct)
            acc[rf][ct] = (float4v)0.f;

    // A staging: thread t stages quads q = t (rows 0..63) and t+512 (rows 64..127)
    const int r0 = t >> 3, kq0 = t & 7;
    const int abase0 = (r0 >> 4)*512 + ((r0 & 15) + ((kq0 >> 1) << 4))*8 + ((kq0 & 1) << 2);
    const int abase1 = abase0 + 4*512;
    const float* xr0 = x + (size_t)(n0 + r0) * DD + kq0 * 4;
    const float* xr1 = xr0 + (size_t)64 * DD;

    auto writeA = [&](int bb, float4 v0, float4 v1) {
        short4v s;
        s[0] = (short)f2bf(v0.x); s[1] = (short)f2bf(v0.y);
        s[2] = (short)f2bf(v0.z); s[3] = (short)f2bf(v0.w);
        *(short4v*)&As[bb][abase0] = s;
        s[0] = (short)f2bf(v1.x); s[1] = (short)f2bf(v1.y);
        s[2] = (short)f2bf(v1.z); s[3] = (short)f2bf(v1.w);
        *(short4v*)&As[bb][abase1] = s;
    };
    // B staging: 1280 16B-slots; uniform 3 ops/thread (256 duplicate slots benign)
    const int q0 = t, q1 = t + 512, q2 = 1024 + (t & 255);
    auto stageB = [&](int bb, int kt) {
        const unsigned short* src = bp + ((size_t)kt * CTN + half * 20) * 512;
        gload_lds16(src + (size_t)q0 * 8, &Bs[bb][q0 * 8]);
        gload_lds16(src + (size_t)q1 * 8, &Bs[bb][q1 * 8]);
        gload_lds16(src + (size_t)q2 * 8, &Bs[bb][q2 * 8]);
    };

    // Per-kt VMEM ops/thread = 5 (3 B-gloads + 2 x-loads). vmcnt(5) at top of
    // iter i => tile-i fully landed; tile-(i+1)'s 5 ops stay in flight.
    auto kbody = [&](int i, int b0, int bstg, float4& cA0, float4& cA1,
                     float4& nA0, float4& nA1) {
        asm volatile("s_waitcnt vmcnt(5) lgkmcnt(0)" ::: "memory");
        __builtin_amdgcn_s_barrier();
        __builtin_amdgcn_sched_barrier(0);
        if (i + 2 < KT) {
            stageB(bstg, i + 2);
            nA0 = *(const float4*)(xr0 + (size_t)(i + 2) * 32);
            nA1 = *(const float4*)(xr1 + (size_t)(i + 2) * 32);
        }
        __builtin_amdgcn_sched_barrier(0);
        short8 af[4];
        #pragma unroll
        for (int rf = 0; rf < 4; ++rf)
            af[rf] = *(const short8*)&As[i & 1][(rg*4 + rf)*512 + lane*8];
        #pragma unroll
        for (int ct = 0; ct < 5; ++ct) {
            short8 bf = *(const short8*)&Bs[b0][((cg*5 + ct)*64 + lane)*8];
            #pragma unroll
            for (int rf = 0; rf < 4; ++rf)
                acc[rf][ct] = __builtin_amdgcn_mfma_f32_16x16x32_bf16(af[rf], bf, acc[rf][ct], 0, 0, 0);
        }
        __builtin_amdgcn_sched_barrier(0);
        if (i + 1 < KT) writeA((i + 1) & 1, cA0, cA1);  // auto-waits cA loads
    };

    // prologue
    float4 pA0a, pA0b, pA1a, pA1b;
    {
        stageB(0, 0);
        float4 a0 = *(const float4*)(xr0);
        float4 a1 = *(const float4*)(xr1);
        stageB(1, 1);
        pA0a = *(const float4*)(xr0 + 32);
        pA0b = *(const float4*)(xr1 + 32);
        __builtin_amdgcn_sched_barrier(0);
        writeA(0, a0, a1);
    }

    int bc = 0;   // ring slot of tile i (= i%3)
    for (int i = 0; i < KT; i += 2) {
        const int b1 = (bc + 1 > 2) ? 0 : bc + 1;
        const int b2 = (bc + 2 > 2) ? bc - 1 : bc + 2;
        kbody(i,     bc, b2, pA0a, pA0b, pA1a, pA1b);
        kbody(i + 1, b1, bc, pA1a, pA1b, pA0a, pA0b);
        bc = b2;
    }

    // bias + bf16 z store (cols half*320 + cg*80 + ct*16 + (lane&15))
    float bv[5];
    const int cb0 = half*320 + cg*80 + (lane & 15);
    #pragma unroll
    for (int ct = 0; ct < 5; ++ct) bv[ct] = bias[cb0 + ct*16];
    #pragma unroll
    for (int rf = 0; rf < 4; ++rf) {
        #pragma unroll
        for (int r = 0; r < 4; ++r) {
            const size_t n = (size_t)(n0 + rg*64 + rf*16 + ((lane >> 4) << 2) + r);
            #pragma unroll
            for (int ct = 0; ct < 5; ++ct)
                z[n*EE + cb0 + ct*16] = f2bf(acc[rf][ct][r] + bv[ct]);
        }
    }
}

// EPI: 2048 blocks x 512 threads; block = 16 rows. All global access coalesced
// via LDS staging; probs via transposed no-atomic column pass. (R10-proven)
__global__ __launch_bounds__(512, 2) void epi2(
    const unsigned short* __restrict__ z, const float* __restrict__ gum,
    const float* __restrict__ cb, float* __restrict__ out,
    float* __restrict__ probs_rep)
{
    __shared__ unsigned short zs[16 * EE];   // 20 KB
    __shared__ float          gs[16 * EE];   // 40 KB
    __shared__ float inv[16][2];
    __shared__ int   sidx[16][2];

    const int t = threadIdx.x;
    const size_t r0 = (size_t)blockIdx.x * 16;

    {
        const uint4* src = (const uint4*)(z + r0 * EE);      // 1280 x 16B
        uint4* dst = (uint4*)zs;
        dst[t]       = src[t];
        dst[t + 512] = src[t + 512];
        if (t < 256) dst[t + 1024] = src[t + 1024];
        const uint4* gsrc = (const uint4*)(gum + r0 * 2 * VV); // 2560 x 16B
        uint4* gdst = (uint4*)gs;
        #pragma unroll
        for (int s = 0; s < 5; ++s) gdst[t + s*512] = gsrc[t + s*512];
    }
    __syncthreads();

    {
        const int row = t >> 5, j = t & 31, g = j >> 4, vb = (j & 15) * 20;
        const unsigned short* zrow = &zs[row * EE + g * VV + vb];
        const float* grow = &gs[row * EE + g * VV + vb];
        float m1 = -1e30f; int bi = 0; float es = 0.f;
        #pragma unroll
        for (int k = 0; k < 20; ++k) {
            const float zj = bf2f(zrow[k]);
            const float zg = zj + grow[k];
            if (zg > m1) { m1 = zg; bi = vb + k; }   // ascending: > keeps first
            es += __expf(zj);
        }
        #pragma unroll
        for (int off = 1; off < 16; off <<= 1) {
            float om = __shfl_xor(m1, off);
            int   ob = __shfl_xor(bi, off);
            if (om > m1 || (om == m1 && ob < bi)) { m1 = om; bi = ob; }
            es += __shfl_xor(es, off);
        }
        if ((j & 15) == 0) { sidx[row][g] = bi; inv[row][g] = 1.f / es; }
    }
    __syncthreads();

    {
        const int rep = blockIdx.x & 7;
        int c = t;
        {
            const int gg = (c >= VV);
            float s = 0.f;
            #pragma unroll
            for (int rr = 0; rr < 16; ++rr)
                s += __expf(bf2f(zs[rr * EE + c])) * inv[rr][gg];
            atomicAdd(&probs_rep[rep * EE + c], s);
        }
        if (t < 128) {
            c = 512 + t;
            float s = 0.f;
            #pragma unroll
            for (int rr = 0; rr < 16; ++rr)
                s += __expf(bf2f(zs[rr * EE + c])) * inv[rr][1];
            atomicAdd(&probs_rep[rep * EE + c], s);
        }
    }

    for (int i = t; i < 16 * 256; i += 512) {
        const int rr = i >> 8, f4 = i & 255;
        const int gg = f4 >> 7;
        const int idx = sidx[rr][gg];
        const float4 v = *(const float4*)&cb[((size_t)gg*VV + idx)*512 + (size_t)(f4 & 127)*4];
        *(float4*)&out[(r0 + rr)*DD + (size_t)f4*4] = v;
    }
}

// perplexity from 8-replica probs accumulator
__global__ void perp8_kernel(const float* __restrict__ probs_rep,
                             float* __restrict__ outp)
{
    __shared__ float s0[4], s1[4];
    int t = threadIdx.x;   // 256
    float p0 = 0.f, p1 = 0.f;
    for (int c = t; c < EE; c += 256) {
        float a = 0.f;
        #pragma unroll
        for (int rp = 0; rp < 8; ++rp) a += probs_rep[rp*EE + c];
        a *= (1.0f / NROWS);
        float v = a * logf(a + 1e-7f);
        if (c < VV) p0 += v; else p1 += v;
    }
    #pragma unroll
    for (int off = 1; off < 64; off <<= 1) {
        p0 += __shfl_xor(p0, off);
        p1 += __shfl_xor(p1, off);
    }
    if ((t & 63) == 0) { s0[t >> 6] = p0; s1[t >> 6] = p1; }
    __syncthreads();
    if (t == 0) {
        float a0 = s0[0] + s0[1] + s0[2] + s0[3];
        float a1 = s1[0] + s1[1] + s1[2] + s1[3];
        outp[0] = 0.5f * (expf(-a0) + expf(-a1));
    }
}

extern "C" void kernel_launch(void* const* d_in, const int* in_sizes, int n_in,
                              void* d_out, int out_size, void* d_ws, size_t ws_size,
                              hipStream_t stream)
{
    const float* x   = (const float*)d_in[0];
    const float* W   = (const float*)d_in[1];
    const float* b   = (const float*)d_in[2];
    const float* cb  = (const float*)d_in[3];
    const float* gum = (const float*)d_in[4];
    float* out = (float*)d_out;

    // ws layout: [bp 1.31MB][probs_rep 20KB][z 41.9MB]
    char* wsp = (char*)d_ws;
    unsigned short* bp = (unsigned short*)wsp;
    const size_t bp_b = (size_t)DD*EE*2;
    float* probs_rep = (float*)(wsp + bp_b);
    const size_t pr_b = 8*EE*sizeof(float);
    unsigned short* z = (unsigned short*)(wsp + bp_b + pr_b);

    hipMemsetAsync(probs_rep, 0, pr_b, stream);
    pack_w<<<320, 256, 0, stream>>>(W, bp);
    gemm_z3<<<512, 512, 0, stream>>>(x, bp, b, z);
    epi2<<<NROWS / 16, 512, 0, stream>>>(z, gum, cb, out, probs_rep);
    perp8_kernel<<<1, 256, 0, stream>>>(probs_rep, out + (out_size - 1));
}

// Round 12
// 142.260 us; speedup vs baseline: 1.6207x; 1.3306x over previous
//
#include <hip/hip_runtime.h>
#include <hip/hip_bf16.h>
#include <math.h>

#define NROWS 32768
#define DD    1024
#define EE    640
#define VV    320
#define BM    128
#define KT    32      // DD/32
#define CTN   40      // EE/16

typedef __attribute__((ext_vector_type(8))) short short8;
typedef __attribute__((ext_vector_type(4))) short short4v;
typedef __attribute__((ext_vector_type(4))) float float4v;

static __device__ __forceinline__ unsigned short f2bf(float f) {
    unsigned int u = __float_as_uint(f);
    return (unsigned short)((u + 0x7fffu + ((u >> 16) & 1u)) >> 16); // RNE
}
static __device__ __forceinline__ float bf2f(unsigned short h) {
    return __uint_as_float(((unsigned int)h) << 16);
}
static __device__ __forceinline__ void gload_lds16(const void* g, void* l) {
    __builtin_amdgcn_global_load_lds(
        (const __attribute__((address_space(1))) unsigned int*)g,
        (__attribute__((address_space(3))) unsigned int*)l, 16, 0, 0);
}

// Pack W [K=1024][N=640] fp32 -> bf16, MFMA fragment layout:
// frag(kt, ct): lane l, elem e  <=  W[kt*32 + (l>>4)*8 + e][ct*16 + (l&15)]
__global__ void pack_w(const float* __restrict__ W, unsigned short* __restrict__ bp)
{
    const int t = threadIdx.x;
    const int tile = blockIdx.x * 4 + (t >> 6);   // 0..1279 = kt*40+ct
    const int lane = t & 63;
    const int kt = tile / CTN, ct = tile % CTN;
    const int k0 = kt * 32 + (lane >> 4) * 8;
    const int col = ct * 16 + (lane & 15);
    unsigned short v1[8];
    #pragma unroll
    for (int e = 0; e < 8; ++e)
        v1[e] = f2bf(W[(size_t)(k0 + e) * EE + col]);
    *(short8*)(bp + ((size_t)tile * 64 + lane) * 8) = *(const short8*)v1;
}

// GEMM (R9-proven, ~68us): 256 blocks x 1024 threads. Block: 128 rows x 640 cols.
// Wave w: rg=w>>3 (64-row half), cg=w&7 (80 cols = 5 frags). acc[4][5].
// B: 3x40KB LDS ring via global_load_lds, counted vmcnt(4) (loads fly across
// barriers); A: 2x8KB dbuf, coalesced fp32 loads 2 tiles ahead.
__global__ __launch_bounds__(1024, 4) void gemm_z_kernel(
    const float* __restrict__ x, const unsigned short* __restrict__ bp,
    const float* __restrict__ bias, unsigned short* __restrict__ z)
{
    __shared__ unsigned short Bs[3][32 * EE];     // 3 x 40 KB ring
    __shared__ unsigned short As[2][BM * 32];     // 2 x 8 KB

    const int t    = threadIdx.x;
    const int lane = t & 63;
    const int w    = t >> 6;            // 0..15
    const int rg   = w >> 3;            // 64-row half
    const int cg   = w & 7;             // 80-col group
    const int n0   = blockIdx.x * BM;

    float4v acc[4][5];
    #pragma unroll
    for (int rf = 0; rf < 4; ++rf)
        #pragma unroll
        for (int ct = 0; ct < 5; ++ct)
            acc[rf][ct] = (float4v)0.f;

    const int r0 = t >> 3, kq0 = t & 7;
    const int abase = (r0 >> 4)*512 + ((r0 & 15) + ((kq0 >> 1) << 4))*8 + ((kq0 & 1) << 2);
    const float* xr = x + (size_t)(n0 + r0) * DD + kq0 * 4;

    auto writeA = [&](int bb, float4 v) {
        short4v s1;
        s1[0] = (short)f2bf(v.x); s1[1] = (short)f2bf(v.y);
        s1[2] = (short)f2bf(v.z); s1[3] = (short)f2bf(v.w);
        *(short4v*)&As[bb][abase] = s1;
    };
    const int q0 = t, q1 = t + 1024, q2 = (t < 512) ? t + 2048 : t + 1536;
    auto stageB = [&](int bb, int kt) {
        const unsigned short* src = bp + (size_t)kt * (32 * EE);
        gload_lds16(src + (size_t)q0 * 8, &Bs[bb][q0 * 8]);
        gload_lds16(src + (size_t)q1 * 8, &Bs[bb][q1 * 8]);
        gload_lds16(src + (size_t)q2 * 8, &Bs[bb][q2 * 8]);
    };

    auto kbody = [&](int i, int b0, int bstg, float4& curA, float4& nxtA) {
        asm volatile("s_waitcnt vmcnt(4) lgkmcnt(0)" ::: "memory");
        __builtin_amdgcn_s_barrier();
        __builtin_amdgcn_sched_barrier(0);
        if (i + 2 < KT) {
            stageB(bstg, i + 2);
            nxtA = *(const float4*)(xr + (size_t)(i + 2) * 32);
        }
        __builtin_amdgcn_sched_barrier(0);
        short8 af[4];
        #pragma unroll
        for (int rf = 0; rf < 4; ++rf)
            af[rf] = *(const short8*)&As[i & 1][(rg*4 + rf)*512 + lane*8];
        #pragma unroll
        for (int ct = 0; ct < 5; ++ct) {
            short8 bf = *(const short8*)&Bs[b0][((cg*5 + ct)*64 + lane)*8];
            #pragma unroll
            for (int rf = 0; rf < 4; ++rf)
                acc[rf][ct] = __builtin_amdgcn_mfma_f32_16x16x32_bf16(af[rf], bf, acc[rf][ct], 0, 0, 0);
        }
        __builtin_amdgcn_sched_barrier(0);
        if (i + 1 < KT) writeA((i + 1) & 1, curA);
    };

    float4 pA0, pA1;
    {
        stageB(0, 0);
        float4 a00 = *(const float4*)(xr);
        stageB(1, 1);
        pA0 = *(const float4*)(xr + 32);
        __builtin_amdgcn_sched_barrier(0);
        writeA(0, a00);
    }

    int bc = 0;
    for (int i = 0; i < KT; i += 2) {
        const int b1 = (bc + 1 > 2) ? 0 : bc + 1;
        const int b2 = (bc + 2 > 2) ? bc - 1 : bc + 2;
        kbody(i,     bc, b2, pA0, pA1);
        kbody(i + 1, b1, bc, pA1, pA0);
        bc = b2;
    }

    // epilogue: bias + bf16 z store (col = (cg>>2)*320 + (cg&3)*80 + (lane&15) + ct*16)
    float bv[5];
    const int cbase = (cg >> 2)*320 + (cg & 3)*80 + (lane & 15);
    #pragma unroll
    for (int ct = 0; ct < 5; ++ct) bv[ct] = bias[cbase + ct*16];
    #pragma unroll
    for (int rf = 0; rf < 4; ++rf) {
        #pragma unroll
        for (int r = 0; r < 4; ++r) {
            const size_t n = (size_t)(n0 + rg*64 + rf*16 + ((lane >> 4) << 2) + r);
            #pragma unroll
            for (int ct = 0; ct < 5; ++ct)
                z[n*EE + cbase + ct*16] = f2bf(acc[rf][ct][r] + bv[ct]);
        }
    }
}

// EPI (R10-proven, ~42us): 2048 blocks x 512 threads; block = 16 rows.
// All global access coalesced via LDS staging; probs via transposed
// no-atomic column pass.
__global__ __launch_bounds__(512, 2) void epi2(
    const unsigned short* __restrict__ z, const float* __restrict__ gum,
    const float* __restrict__ cb, float* __restrict__ out,
    float* __restrict__ probs_rep)
{
    __shared__ unsigned short zs[16 * EE];   // 20 KB
    __shared__ float          gs[16 * EE];   // 40 KB
    __shared__ float inv[16][2];
    __shared__ int   sidx[16][2];

    const int t = threadIdx.x;
    const size_t r0 = (size_t)blockIdx.x * 16;

    {
        const uint4* src = (const uint4*)(z + r0 * EE);      // 1280 x 16B
        uint4* dst = (uint4*)zs;
        dst[t]       = src[t];
        dst[t + 512] = src[t + 512];
        if (t < 256) dst[t + 1024] = src[t + 1024];
        const uint4* gsrc = (const uint4*)(gum + r0 * 2 * VV); // 2560 x 16B
        uint4* gdst = (uint4*)gs;
        #pragma unroll
        for (int s = 0; s < 5; ++s) gdst[t + s*512] = gsrc[t + s*512];
    }
    __syncthreads();

    {
        const int row = t >> 5, j = t & 31, g = j >> 4, vb = (j & 15) * 20;
        const unsigned short* zrow = &zs[row * EE + g * VV + vb];
        const float* grow = &gs[row * EE + g * VV + vb];
        float m1 = -1e30f; int bi = 0; float es = 0.f;
        #pragma unroll
        for (int k = 0; k < 20; ++k) {
            const float zj = bf2f(zrow[k]);
            const float zg = zj + grow[k];
            if (zg > m1) { m1 = zg; bi = vb + k; }   // ascending: > keeps first
            es += __expf(zj);
        }
        #pragma unroll
        for (int off = 1; off < 16; off <<= 1) {
            float om = __shfl_xor(m1, off);
            int   ob = __shfl_xor(bi, off);
            if (om > m1 || (om == m1 && ob < bi)) { m1 = om; bi = ob; }
            es += __shfl_xor(es, off);
        }
        if ((j & 15) == 0) { sidx[row][g] = bi; inv[row][g] = 1.f / es; }
    }
    __syncthreads();

    {
        const int rep = blockIdx.x & 7;
        int c = t;
        {
            const int gg = (c >= VV);
            float s = 0.f;
            #pragma unroll
            for (int rr = 0; rr < 16; ++rr)
                s += __expf(bf2f(zs[rr * EE + c])) * inv[rr][gg];
            atomicAdd(&probs_rep[rep * EE + c], s);
        }
        if (t < 128) {
            c = 512 + t;
            float s = 0.f;
            #pragma unroll
            for (int rr = 0; rr < 16; ++rr)
                s += __expf(bf2f(zs[rr * EE + c])) * inv[rr][1];
            atomicAdd(&probs_rep[rep * EE + c], s);
        }
    }

    for (int i = t; i < 16 * 256; i += 512) {
        const int rr = i >> 8, f4 = i & 255;
        const int gg = f4 >> 7;
        const int idx = sidx[rr][gg];
        const float4 v = *(const float4*)&cb[((size_t)gg*VV + idx)*512 + (size_t)(f4 & 127)*4];
        *(float4*)&out[(r0 + rr)*DD + (size_t)f4*4] = v;
    }
}

// perplexity from 8-replica probs accumulator
__global__ void perp8_kernel(const float* __restrict__ probs_rep,
                             float* __restrict__ outp)
{
    __shared__ float s0[4], s1[4];
    int t = threadIdx.x;   // 256
    float p0 = 0.f, p1 = 0.f;
    for (int c = t; c < EE; c += 256) {
        float a = 0.f;
        #pragma unroll
        for (int rp = 0; rp < 8; ++rp) a += probs_rep[rp*EE + c];
        a *= (1.0f / NROWS);
        float v = a * logf(a + 1e-7f);
        if (c < VV) p0 += v; else p1 += v;
    }
    #pragma unroll
    for (int off = 1; off < 64; off <<= 1) {
        p0 += __shfl_xor(p0, off);
        p1 += __shfl_xor(p1, off);
    }
    if ((t & 63) == 0) { s0[t >> 6] = p0; s1[t >> 6] = p1; }
    __syncthreads();
    if (t == 0) {
        float a0 = s0[0] + s0[1] + s0[2] + s0[3];
        float a1 = s1[0] + s1[1] + s1[2] + s1[3];
        outp[0] = 0.5f * (expf(-a0) + expf(-a1));
    }
}

extern "C" void kernel_launch(void* const* d_in, const int* in_sizes, int n_in,
                              void* d_out, int out_size, void* d_ws, size_t ws_size,
                              hipStream_t stream)
{
    const float* x   = (const float*)d_in[0];
    const float* W   = (const float*)d_in[1];
    const float* b   = (const float*)d_in[2];
    const float* cb  = (const float*)d_in[3];
    const float* gum = (const float*)d_in[4];
    float* out = (float*)d_out;

    // ws layout: [bp 1.31MB][probs_rep 20KB][z 41.9MB]
    char* wsp = (char*)d_ws;
    unsigned short* bp = (unsigned short*)wsp;
    const size_t bp_b = (size_t)DD*EE*2;
    float* probs_rep = (float*)(wsp + bp_b);
    const size_t pr_b = 8*EE*sizeof(float);
    unsigned short* z = (unsigned short*)(wsp + bp_b + pr_b);

    hipMemsetAsync(probs_rep, 0, pr_b, stream);
    pack_w<<<320, 256, 0, stream>>>(W, bp);
    gemm_z_kernel<<<NROWS / BM, 1024, 0, stream>>>(x, bp, b, z);
    epi2<<<NROWS / 16, 512, 0, stream>>>(z, gum, cb, out, probs_rep);
    perp8_kernel<<<1, 256, 0, stream>>>(probs_rep, out + (out_size - 1));
}